// Round 4
// baseline (170.203 us; speedup 1.0000x reference)
//
#include <hip/hip_runtime.h>
#include <hip/hip_cooperative_groups.h>
#include <hip/hip_bf16.h>
#include <cstddef>
#include <cstdint>

#define EPSV 1e-3f
#define LOG2E 1.4426950408889634f

using f32x4 = __attribute__((ext_vector_type(4))) float;
using bh8   = __attribute__((ext_vector_type(8))) short;   // 8 bf16

#if defined(__has_builtin)
#  if __has_builtin(__builtin_amdgcn_exp2f)
#    define EXP2F(v) __builtin_amdgcn_exp2f(v)
#  else
#    define EXP2F(v) exp2f(v)
#  endif
#else
#  define EXP2F(v) exp2f(v)
#endif

static __device__ __forceinline__ short bfs(float f) {
    __hip_bfloat16 h = __float2bfloat16(f);
    return *reinterpret_cast<short*>(&h);
}

struct SMProj {
    float lx[32*65];
    float lw[3*2048];
    float lbias[96];
};
struct SMAttn {
    float yl[4][32][33];
    float lred[4][32];
    float lwW[2048];
    float lwb[64];
    __align__(16) float wys[32*68];      // per-block pre-BN w_y tile (stays in LDS)
    float red1[256];
    float red2[256];
    __align__(16) float params[128];     // BN scale/shift
};
union SMU { SMProj p; SMAttn a; };

// ---------------------------------------------------------------------------
// One cooperative kernel, 512 blocks x 256 threads, 2 grid syncs.
// Block blk owns pixels [blk*32, blk*32+32) for proj, attn AND apply.
// g stored PRE-SHUFFLED transposed gshuf[b][d][4096] with kappa(h,i) key
// order (verified rounds 1-3); theta pre-scaled by log2(e) so softmax uses
// native exp2.
// ---------------------------------------------------------------------------
__global__ __launch_bounds__(256, 2) void fused_kernel(
    const float* __restrict__ x,
    const float* __restrict__ gW, const float* __restrict__ gbias,
    const float* __restrict__ pW, const float* __restrict__ pbias,
    const float* __restrict__ tW, const float* __restrict__ tbias,
    const float* __restrict__ wW, const float* __restrict__ wb,
    const float* __restrict__ gamma, const float* __restrict__ beta,
    __hip_bfloat16* __restrict__ thetab,
    __hip_bfloat16* __restrict__ phib,
    __hip_bfloat16* __restrict__ gshuf,
    float* __restrict__ stats,
    float* __restrict__ out)
{
    namespace cg = cooperative_groups;
    cg::grid_group grid = cg::this_grid();
    __shared__ SMU sm;

    const int tid = threadIdx.x;
    const int blk = blockIdx.x;
    const int pix0 = blk * 32;

    // ================= Phase 1: projections =================
    {
        #pragma unroll
        for (int j = 0; j < 8; ++j) {      // 2048 floats of x
            int idx = tid + 256*j;
            sm.p.lx[(idx >> 6)*65 + (idx & 63)] = x[(size_t)pix0*64 + idx];
        }
        #pragma unroll
        for (int j = 0; j < 8; ++j) {
            int idx = tid + 256*j;
            sm.p.lw[idx]        = tW[idx];
            sm.p.lw[2048 + idx] = pW[idx];
            sm.p.lw[4096 + idx] = gW[idx];
        }
        if (tid < 32) {
            sm.p.lbias[tid]      = tbias[tid];
            sm.p.lbias[32 + tid] = pbias[tid];
            sm.p.lbias[64 + tid] = gbias[tid];
        }
        __syncthreads();

        const int p  = tid & 31;
        const int og = tid >> 5;           // 0..7 -> 12 outputs each (96 total)
        const int obase = og*12;
        float acc[12];
        #pragma unroll
        for (int j = 0; j < 12; ++j) acc[j] = 0.f;
        for (int c = 0; c < 64; ++c) {
            float xc = sm.p.lx[p*65 + c];
            #pragma unroll
            for (int j = 0; j < 12; ++j) {
                int o = obase + j;
                acc[j] += xc * sm.p.lw[(o >> 5)*2048 + c*32 + (o & 31)];
            }
        }
        const int pix = pix0 + p;
        const int b = pix >> 12;
        const int n = pix & 4095;
        const int loc = n & 31;
        const int t  = (loc >> 4) & 1;
        const int hh = (loc >> 2) & 3;
        const int jj = loc & 3;
        const int pos = (n & ~31) + 8*hh + jj + 4*t;
        #pragma unroll
        for (int j = 0; j < 12; ++j) {
            int o = obase + j;
            float v = acc[j] + sm.p.lbias[o];
            if (o < 32) {
                thetab[(size_t)pix*32 + o] = __float2bfloat16(v * LOG2E);
            } else if (o < 64) {
                phib[(size_t)pix*32 + (o-32)] = __float2bfloat16(v);
            } else {
                gshuf[((size_t)b*32 + (o-64))*4096 + pos] = __float2bfloat16(v);
            }
        }
    }

    grid.sync();

    // ================= Phase 2: attention + w_y + stats =================
    {
        const int wave = tid >> 6;
        const int lane = tid & 63;
        const int h = lane >> 4;
        const int r = lane & 15;
        const int b = blk >> 7;
        const int q0 = (blk & 127) * 32;
        const size_t base = (size_t)b * 4096;

        #pragma unroll
        for (int j = 0; j < 8; ++j) sm.a.lwW[tid + 256*j] = wW[tid + 256*j];
        if (tid < 64) sm.a.lwb[tid] = wb[tid];

        const bh8 qaA = *(const bh8*)(thetab + (base + q0 + r)*32 + h*8);
        const bh8 qaB = *(const bh8*)(thetab + (base + q0 + 16 + r)*32 + h*8);
        const __hip_bfloat16* phiB = phib  + base*32;
        const __hip_bfloat16* gB   = gshuf + base*32;

        f32x4 y0A = {0,0,0,0}, y1A = {0,0,0,0};
        f32x4 y0B = {0,0,0,0}, y1B = {0,0,0,0};
        float lsA = 0.f, lsB = 0.f;

        const int kbeg = wave * 1024;
        const int kend = kbeg + 1024;
        bh8 ka = *(const bh8*)(phiB + (size_t)(kbeg + r)*32 + h*8);
        bh8 kb = *(const bh8*)(phiB + (size_t)(kbeg + 16 + r)*32 + h*8);
        bh8 g0 = *(const bh8*)(gB + (size_t)r*4096 + kbeg + 8*h);
        bh8 g1 = *(const bh8*)(gB + (size_t)(16 + r)*4096 + kbeg + 8*h);

        for (int kk = kbeg; kk < kend; kk += 32) {
            const int nk = (kk + 32 < kend) ? (kk + 32) : kbeg;   // depth-1 prefetch
            bh8 ka2 = *(const bh8*)(phiB + (size_t)(nk + r)*32 + h*8);
            bh8 kb2 = *(const bh8*)(phiB + (size_t)(nk + 16 + r)*32 + h*8);
            bh8 g02 = *(const bh8*)(gB + (size_t)r*4096 + nk + 8*h);
            bh8 g12 = *(const bh8*)(gB + (size_t)(16 + r)*4096 + nk + 8*h);

            f32x4 z = {0,0,0,0};
            f32x4 s0A = __builtin_amdgcn_mfma_f32_16x16x32_bf16(ka, qaA, z, 0, 0, 0);
            f32x4 s1A = __builtin_amdgcn_mfma_f32_16x16x32_bf16(kb, qaA, z, 0, 0, 0);
            f32x4 s0B = __builtin_amdgcn_mfma_f32_16x16x32_bf16(ka, qaB, z, 0, 0, 0);
            f32x4 s1B = __builtin_amdgcn_mfma_f32_16x16x32_bf16(kb, qaB, z, 0, 0, 0);

            float pA0 = EXP2F(s0A[0]), pA1 = EXP2F(s0A[1]), pA2 = EXP2F(s0A[2]), pA3 = EXP2F(s0A[3]);
            float pA4 = EXP2F(s1A[0]), pA5 = EXP2F(s1A[1]), pA6 = EXP2F(s1A[2]), pA7 = EXP2F(s1A[3]);
            float pB0 = EXP2F(s0B[0]), pB1 = EXP2F(s0B[1]), pB2 = EXP2F(s0B[2]), pB3 = EXP2F(s0B[3]);
            float pB4 = EXP2F(s1B[0]), pB5 = EXP2F(s1B[1]), pB6 = EXP2F(s1B[2]), pB7 = EXP2F(s1B[3]);
            lsA += ((pA0+pA1)+(pA2+pA3)) + ((pA4+pA5)+(pA6+pA7));
            lsB += ((pB0+pB1)+(pB2+pB3)) + ((pB4+pB5)+(pB6+pB7));

            bh8 paA, paB;
            paA[0]=bfs(pA0); paA[1]=bfs(pA1); paA[2]=bfs(pA2); paA[3]=bfs(pA3);
            paA[4]=bfs(pA4); paA[5]=bfs(pA5); paA[6]=bfs(pA6); paA[7]=bfs(pA7);
            paB[0]=bfs(pB0); paB[1]=bfs(pB1); paB[2]=bfs(pB2); paB[3]=bfs(pB3);
            paB[4]=bfs(pB4); paB[5]=bfs(pB5); paB[6]=bfs(pB6); paB[7]=bfs(pB7);

            y0A = __builtin_amdgcn_mfma_f32_16x16x32_bf16(paA, g0, y0A, 0, 0, 0);
            y1A = __builtin_amdgcn_mfma_f32_16x16x32_bf16(paA, g1, y1A, 0, 0, 0);
            y0B = __builtin_amdgcn_mfma_f32_16x16x32_bf16(paB, g0, y0B, 0, 0, 0);
            y1B = __builtin_amdgcn_mfma_f32_16x16x32_bf16(paB, g1, y1B, 0, 0, 0);

            ka = ka2; kb = kb2; g0 = g02; g1 = g12;
        }

        lsA += __shfl_xor(lsA, 16); lsA += __shfl_xor(lsA, 32);
        lsB += __shfl_xor(lsB, 16); lsB += __shfl_xor(lsB, 32);

        #pragma unroll
        for (int gi = 0; gi < 4; ++gi) {
            sm.a.yl[wave][4*h+gi][r]       = y0A[gi];
            sm.a.yl[wave][4*h+gi][16+r]    = y1A[gi];
            sm.a.yl[wave][16+4*h+gi][r]    = y0B[gi];
            sm.a.yl[wave][16+4*h+gi][16+r] = y1B[gi];
        }
        if (lane < 16) { sm.a.lred[wave][r] = lsA; sm.a.lred[wave][16+r] = lsB; }
        __syncthreads();

        // combine waves + normalize -> yl[0][q][d]
        {
            const int q  = tid >> 3;
            const int d4 = (tid & 7) * 4;
            float a0=0, a1=0, a2=0, a3=0;
            #pragma unroll
            for (int w = 0; w < 4; ++w) {
                a0 += sm.a.yl[w][q][d4+0]; a1 += sm.a.yl[w][q][d4+1];
                a2 += sm.a.yl[w][q][d4+2]; a3 += sm.a.yl[w][q][d4+3];
            }
            float lq = (sm.a.lred[0][q] + sm.a.lred[1][q]) + (sm.a.lred[2][q] + sm.a.lred[3][q]);
            float inv = 1.0f / lq;
            sm.a.yl[0][q][d4+0] = a0*inv;
            sm.a.yl[0][q][d4+1] = a1*inv;
            sm.a.yl[0][q][d4+2] = a2*inv;
            sm.a.yl[0][q][d4+3] = a3*inv;
        }
        __syncthreads();

        // w_y = y @ w_W + w_b -> LDS wys; per-block channel sum/sumsq -> stats
        {
            const int p  = tid & 31;
            const int cg_ = tid >> 5;          // 0..7 -> channels cg*8..cg*8+7
            float acc[8];
            #pragma unroll
            for (int j = 0; j < 8; ++j) acc[j] = sm.a.lwb[cg_*8 + j];
            for (int d = 0; d < 32; ++d) {
                float yv = sm.a.yl[0][p][d];
                #pragma unroll
                for (int j = 0; j < 8; ++j) acc[j] += yv * sm.a.lwW[d*64 + cg_*8 + j];
            }
            *(float4*)&sm.a.wys[p*68 + cg_*8]     = *(float4*)&acc[0];
            *(float4*)&sm.a.wys[p*68 + cg_*8 + 4] = *(float4*)&acc[4];

            float s1[8], s2[8];
            #pragma unroll
            for (int j = 0; j < 8; ++j) { s1[j] = acc[j]; s2[j] = acc[j]*acc[j]; }
            #pragma unroll
            for (int m = 1; m <= 16; m <<= 1) {
                #pragma unroll
                for (int j = 0; j < 8; ++j) {
                    s1[j] += __shfl_xor(s1[j], m);
                    s2[j] += __shfl_xor(s2[j], m);
                }
            }
            if (p == 0) {
                #pragma unroll
                for (int j = 0; j < 8; ++j) {
                    stats[(size_t)blk*128 + cg_*8 + j]      = s1[j];
                    stats[(size_t)blk*128 + 64 + cg_*8 + j] = s2[j];
                }
            }
        }
    }

    grid.sync();

    // ================= Phase 3: stats reduce -> BN params (per block) =======
    {
        const int c = tid & 63, part = tid >> 6;
        float s1 = 0.f, s2 = 0.f;
        for (int k = part*128; k < part*128 + 128; ++k) {
            s1 += stats[(size_t)k*128 + c];
            s2 += stats[(size_t)k*128 + 64 + c];
        }
        sm.a.red1[tid] = s1;
        sm.a.red2[tid] = s2;
        __syncthreads();
        if (tid < 64) {
            float t1 = sm.a.red1[tid] + sm.a.red1[64+tid] + sm.a.red1[128+tid] + sm.a.red1[192+tid];
            float t2 = sm.a.red2[tid] + sm.a.red2[64+tid] + sm.a.red2[128+tid] + sm.a.red2[192+tid];
            float mean = t1 * (1.0f/16384.0f);
            float var  = t2 * (1.0f/16384.0f) - mean*mean;
            float sc = gamma[tid] * rsqrtf(var + EPSV);
            sm.a.params[tid]      = sc;
            sm.a.params[64 + tid] = beta[tid] - mean*sc;
        }
        __syncthreads();
    }

    // ================= Phase 4: out = x + sc*w_y + sh =================
    {
        #pragma unroll
        for (int j = 0; j < 2; ++j) {
            int idx = tid + 256*j;             // 0..511 float4s
            int p  = idx >> 4;
            int c4 = (idx & 15) * 4;
            float4 xv = *(const float4*)(x + ((size_t)pix0 + p)*64 + c4);
            float4 wv = *(const float4*)&sm.a.wys[p*68 + c4];
            float4 sc = *(const float4*)&sm.a.params[c4];
            float4 sh = *(const float4*)&sm.a.params[64 + c4];
            float4 rr;
            rr.x = xv.x + sc.x*wv.x + sh.x;
            rr.y = xv.y + sc.y*wv.y + sh.y;
            rr.z = xv.z + sc.z*wv.z + sh.z;
            rr.w = xv.w + sc.w*wv.w + sh.w;
            *(float4*)(out + ((size_t)pix0 + p)*64 + c4) = rr;
        }
    }
}

// ---------------------------------------------------------------------------
extern "C" void kernel_launch(void* const* d_in, const int* in_sizes, int n_in,
                              void* d_out, int out_size, void* d_ws, size_t ws_size,
                              hipStream_t stream)
{
    const float* x     = (const float*)d_in[0];
    const float* gW    = (const float*)d_in[1];
    const float* gb    = (const float*)d_in[2];
    const float* pW    = (const float*)d_in[3];
    const float* pb    = (const float*)d_in[4];
    const float* tW    = (const float*)d_in[5];
    const float* tb    = (const float*)d_in[6];
    const float* wW    = (const float*)d_in[7];
    const float* wb    = (const float*)d_in[8];
    const float* gamma = (const float*)d_in[9];
    const float* beta  = (const float*)d_in[10];
    float* out = (float*)d_out;

    char* w = (char*)d_ws;
    __hip_bfloat16* thetab = (__hip_bfloat16*)(w);                 // 1 MB
    __hip_bfloat16* phib   = (__hip_bfloat16*)(w + (1u<<20));      // 1 MB
    __hip_bfloat16* gshuf  = (__hip_bfloat16*)(w + (2u<<20));      // 1 MB
    float* stats  = (float*)(w + (3u<<20));                        // 256 KB

    void* args[] = {
        (void*)&x, (void*)&gW, (void*)&gb, (void*)&pW, (void*)&pb,
        (void*)&tW, (void*)&tb, (void*)&wW, (void*)&wb,
        (void*)&gamma, (void*)&beta,
        (void*)&thetab, (void*)&phib, (void*)&gshuf,
        (void*)&stats, (void*)&out
    };
    hipLaunchCooperativeKernel((const void*)fused_kernel,
                               dim3(512), dim3(256), args, 0, stream);
}

// Round 5
// 80.346 us; speedup vs baseline: 2.1184x; 2.1184x over previous
//
#include <hip/hip_runtime.h>
#include <hip/hip_bf16.h>
#include <cstddef>
#include <cstdint>

#define EPSV 1e-3f
#define LOG2E 1.4426950408889634f

using f32x4 = __attribute__((ext_vector_type(4))) float;
using bh8   = __attribute__((ext_vector_type(8))) short;   // 8 bf16

#if defined(__has_builtin)
#  if __has_builtin(__builtin_amdgcn_exp2f)
#    define EXP2F(v) __builtin_amdgcn_exp2f(v)
#  else
#    define EXP2F(v) exp2f(v)
#  endif
#else
#  define EXP2F(v) exp2f(v)
#endif

static __device__ __forceinline__ short bfs(float f) {
    __hip_bfloat16 h = __float2bfloat16(f);
    return *reinterpret_cast<short*>(&h);
}

// ---------------------------------------------------------------------------
// Kernel 1: projections. 512 blocks x 32 pixels. theta/phi: [pix][32] bf16;
// theta pre-scaled by log2(e) so attention uses native exp2.
// g stored PRE-SHUFFLED transposed gshuf[b][d][4096]; within each 32-key
// chunk, position 8h+i holds key kappa(h,i) = i<4 ? 4h+i : 16+4h+(i-4),
// matching the PV A-fragment key order (verified rounds 1-4 passing).
// ---------------------------------------------------------------------------
__global__ __launch_bounds__(256) void proj_kernel(
    const float* __restrict__ x,
    const float* __restrict__ gW, const float* __restrict__ gbias,
    const float* __restrict__ pW, const float* __restrict__ pbias,
    const float* __restrict__ tW, const float* __restrict__ tbias,
    __hip_bfloat16* __restrict__ thetab,
    __hip_bfloat16* __restrict__ phib,
    __hip_bfloat16* __restrict__ gshuf)
{
    __shared__ float lx[32*65];
    __shared__ float lw[3*2048];       // theta, phi, g weights [64c][32o]
    __shared__ float lbias[96];
    const int tid = threadIdx.x;
    const int pix0 = blockIdx.x * 32;

    #pragma unroll
    for (int j = 0; j < 8; ++j) {      // 2048 floats of x
        int idx = tid + 256*j;
        lx[(idx >> 6)*65 + (idx & 63)] = x[(size_t)pix0*64 + idx];
    }
    #pragma unroll
    for (int j = 0; j < 8; ++j) {
        int idx = tid + 256*j;
        lw[idx]        = tW[idx];
        lw[2048 + idx] = pW[idx];
        lw[4096 + idx] = gW[idx];
    }
    if (tid < 32) { lbias[tid] = tbias[tid]; lbias[32+tid] = pbias[tid]; lbias[64+tid] = gbias[tid]; }
    __syncthreads();

    const int p  = tid & 31;
    const int og = tid >> 5;           // 0..7 -> 12 outputs each (96 total)
    const int obase = og*12;
    float acc[12];
    #pragma unroll
    for (int j = 0; j < 12; ++j) acc[j] = 0.f;
    for (int c = 0; c < 64; ++c) {
        float xc = lx[p*65 + c];
        #pragma unroll
        for (int j = 0; j < 12; ++j) {
            int o = obase + j;
            acc[j] += xc * lw[(o >> 5)*2048 + c*32 + (o & 31)];
        }
    }
    const int pix = pix0 + p;
    const int b = pix >> 12;
    const int n = pix & 4095;
    const int loc = n & 31;
    const int t  = (loc >> 4) & 1;
    const int hh = (loc >> 2) & 3;
    const int jj = loc & 3;
    const int pos = (n & ~31) + 8*hh + jj + 4*t;
    #pragma unroll
    for (int j = 0; j < 12; ++j) {
        int o = obase + j;
        float v = acc[j] + lbias[o];
        if (o < 32)       thetab[(size_t)pix*32 + o] = __float2bfloat16(v * LOG2E);
        else if (o < 64)  phib[(size_t)pix*32 + (o-32)] = __float2bfloat16(v);
        else              gshuf[((size_t)b*32 + (o-64))*4096 + pos] = __float2bfloat16(v);
    }
}

// ---------------------------------------------------------------------------
// Kernel 2: fused flash-attention + output conv + BN partial stats.
// 512 blocks (4 batch x 128 qtiles of 32 queries), EIGHT waves; wave w covers
// keys [w*512, w*512+512)  -> 16 waves/CU = 4 waves/SIMD latency hiding.
// Swapped-operand QK^T (mfma(K,Q)) + kmap-baked gshuf: exp'd scores feed PV
// A-fragment directly. Cross-wave combine in LDS -> normalized y ->
// y @ w_W + w_b -> out (pre-BN), plus per-block channel sum/sumsq -> stats.
// ---------------------------------------------------------------------------
__global__ __launch_bounds__(512, 4) void attn_kernel(
    const __hip_bfloat16* __restrict__ thetab,
    const __hip_bfloat16* __restrict__ phib,
    const __hip_bfloat16* __restrict__ gshuf,
    const float* __restrict__ wW, const float* __restrict__ wb,
    float* __restrict__ out, float* __restrict__ stats)
{
    __shared__ float yl[8][32][33];
    __shared__ float lred[8][32];
    __shared__ float lwW[2048];
    __shared__ float lwb[64];
    const int tid  = threadIdx.x;
    const int wave = tid >> 6;
    const int lane = tid & 63;
    const int h = lane >> 4;
    const int r = lane & 15;
    const int blk = blockIdx.x;
    const int b = blk >> 7;
    const int q0 = (blk & 127) * 32;
    const size_t base = (size_t)b * 4096;

    #pragma unroll
    for (int j = 0; j < 4; ++j) lwW[tid + 512*j] = wW[tid + 512*j];
    if (tid < 64) lwb[tid] = wb[tid];

    const bh8 qaA = *(const bh8*)(thetab + (base + q0 + r)*32 + h*8);
    const bh8 qaB = *(const bh8*)(thetab + (base + q0 + 16 + r)*32 + h*8);
    const __hip_bfloat16* phiB = phib  + base*32;
    const __hip_bfloat16* gB   = gshuf + base*32;

    f32x4 y0A = {0,0,0,0}, y1A = {0,0,0,0};
    f32x4 y0B = {0,0,0,0}, y1B = {0,0,0,0};
    float lsA = 0.f, lsB = 0.f;

    const int kbeg = wave * 512;
    const int kend = kbeg + 512;
    bh8 ka = *(const bh8*)(phiB + (size_t)(kbeg + r)*32 + h*8);
    bh8 kb = *(const bh8*)(phiB + (size_t)(kbeg + 16 + r)*32 + h*8);
    bh8 g0 = *(const bh8*)(gB + (size_t)r*4096 + kbeg + 8*h);
    bh8 g1 = *(const bh8*)(gB + (size_t)(16 + r)*4096 + kbeg + 8*h);

    for (int kk = kbeg; kk < kend; kk += 32) {
        const int nk = (kk + 32 < kend) ? (kk + 32) : kbeg;   // depth-1 prefetch
        bh8 ka2 = *(const bh8*)(phiB + (size_t)(nk + r)*32 + h*8);
        bh8 kb2 = *(const bh8*)(phiB + (size_t)(nk + 16 + r)*32 + h*8);
        bh8 g02 = *(const bh8*)(gB + (size_t)r*4096 + nk + 8*h);
        bh8 g12 = *(const bh8*)(gB + (size_t)(16 + r)*4096 + nk + 8*h);

        f32x4 z = {0,0,0,0};
        f32x4 s0A = __builtin_amdgcn_mfma_f32_16x16x32_bf16(ka, qaA, z, 0, 0, 0);
        f32x4 s1A = __builtin_amdgcn_mfma_f32_16x16x32_bf16(kb, qaA, z, 0, 0, 0);
        f32x4 s0B = __builtin_amdgcn_mfma_f32_16x16x32_bf16(ka, qaB, z, 0, 0, 0);
        f32x4 s1B = __builtin_amdgcn_mfma_f32_16x16x32_bf16(kb, qaB, z, 0, 0, 0);

        float pA0 = EXP2F(s0A[0]), pA1 = EXP2F(s0A[1]), pA2 = EXP2F(s0A[2]), pA3 = EXP2F(s0A[3]);
        float pA4 = EXP2F(s1A[0]), pA5 = EXP2F(s1A[1]), pA6 = EXP2F(s1A[2]), pA7 = EXP2F(s1A[3]);
        float pB0 = EXP2F(s0B[0]), pB1 = EXP2F(s0B[1]), pB2 = EXP2F(s0B[2]), pB3 = EXP2F(s0B[3]);
        float pB4 = EXP2F(s1B[0]), pB5 = EXP2F(s1B[1]), pB6 = EXP2F(s1B[2]), pB7 = EXP2F(s1B[3]);
        lsA += ((pA0+pA1)+(pA2+pA3)) + ((pA4+pA5)+(pA6+pA7));
        lsB += ((pB0+pB1)+(pB2+pB3)) + ((pB4+pB5)+(pB6+pB7));

        bh8 paA, paB;
        paA[0]=bfs(pA0); paA[1]=bfs(pA1); paA[2]=bfs(pA2); paA[3]=bfs(pA3);
        paA[4]=bfs(pA4); paA[5]=bfs(pA5); paA[6]=bfs(pA6); paA[7]=bfs(pA7);
        paB[0]=bfs(pB0); paB[1]=bfs(pB1); paB[2]=bfs(pB2); paB[3]=bfs(pB3);
        paB[4]=bfs(pB4); paB[5]=bfs(pB5); paB[6]=bfs(pB6); paB[7]=bfs(pB7);

        y0A = __builtin_amdgcn_mfma_f32_16x16x32_bf16(paA, g0, y0A, 0, 0, 0);
        y1A = __builtin_amdgcn_mfma_f32_16x16x32_bf16(paA, g1, y1A, 0, 0, 0);
        y0B = __builtin_amdgcn_mfma_f32_16x16x32_bf16(paB, g0, y0B, 0, 0, 0);
        y1B = __builtin_amdgcn_mfma_f32_16x16x32_bf16(paB, g1, y1B, 0, 0, 0);

        ka = ka2; kb = kb2; g0 = g02; g1 = g12;
    }

    lsA += __shfl_xor(lsA, 16); lsA += __shfl_xor(lsA, 32);
    lsB += __shfl_xor(lsB, 16); lsB += __shfl_xor(lsB, 32);

    #pragma unroll
    for (int gi = 0; gi < 4; ++gi) {
        yl[wave][4*h+gi][r]       = y0A[gi];
        yl[wave][4*h+gi][16+r]    = y1A[gi];
        yl[wave][16+4*h+gi][r]    = y0B[gi];
        yl[wave][16+4*h+gi][16+r] = y1B[gi];
    }
    if (lane < 16) { lred[wave][r] = lsA; lred[wave][16+r] = lsB; }
    __syncthreads();

    // Phase B: combine 8 waves + normalize -> yl[0][q][d]. Each of the 512
    // threads owns (q = tid>>4, d2 = (tid&15)*2 .. +1): reads all waves' cells
    // and overwrites only its own yl[0] cells -> no cross-thread hazard.
    {
        const int q  = tid >> 4;
        const int d2 = (tid & 15) * 2;
        float a0 = 0.f, a1 = 0.f, lq = 0.f;
        #pragma unroll
        for (int w = 0; w < 8; ++w) {
            a0 += yl[w][q][d2];
            a1 += yl[w][q][d2+1];
            lq += lred[w][q];
        }
        float inv = 1.0f / lq;
        yl[0][q][d2]   = a0*inv;
        yl[0][q][d2+1] = a1*inv;
    }
    __syncthreads();

    // Phase C: w_y = y @ w_W + w_b -> out (pre-BN); channel sum/sumsq -> stats.
    {
        const int p   = tid & 31;
        const int cg_ = tid >> 5;          // 0..15 -> channels cg*4..cg*4+3
        float acc[4];
        #pragma unroll
        for (int j = 0; j < 4; ++j) acc[j] = lwb[cg_*4 + j];
        for (int d = 0; d < 32; ++d) {
            float yv = yl[0][p][d];
            #pragma unroll
            for (int j = 0; j < 4; ++j) acc[j] += yv * lwW[d*64 + cg_*4 + j];
        }
        float4 st = { acc[0], acc[1], acc[2], acc[3] };
        *(float4*)(out + (size_t)(base + q0 + p)*64 + cg_*4) = st;

        float s1[4], s2[4];
        #pragma unroll
        for (int j = 0; j < 4; ++j) { s1[j] = acc[j]; s2[j] = acc[j]*acc[j]; }
        #pragma unroll
        for (int m = 1; m <= 16; m <<= 1) {
            #pragma unroll
            for (int j = 0; j < 4; ++j) {
                s1[j] += __shfl_xor(s1[j], m);
                s2[j] += __shfl_xor(s2[j], m);
            }
        }
        if (p == 0) {                       // lanes 0 and 32 of each wave
            #pragma unroll
            for (int j = 0; j < 4; ++j) {
                stats[(size_t)blk*128 + cg_*4 + j]      = s1[j];
                stats[(size_t)blk*128 + 64 + cg_*4 + j] = s2[j];
            }
        }
    }
}

// ---------------------------------------------------------------------------
// Kernel 3: fused BN-finalize + apply. 256 blocks x 256 threads.
// Every block redundantly reduces the 512x128 stat partials (16 MB L2 total),
// computes scale/shift in LDS, then out = x + sc*w_y + sh for its 1024
// float4 slice (w_y currently in d_out).
// ---------------------------------------------------------------------------
__global__ __launch_bounds__(256) void apply_kernel(
    const float* __restrict__ stats,
    const float* __restrict__ gamma,
    const float* __restrict__ beta,
    const float* __restrict__ x,
    float* __restrict__ out)
{
    __shared__ float r1[256];
    __shared__ float r2[256];
    __shared__ __align__(16) float params[128];
    const int tid = threadIdx.x;
    {
        const int c = tid & 63, part = tid >> 6;
        float s1 = 0.f, s2 = 0.f;
        for (int k = part*128; k < part*128 + 128; ++k) {
            s1 += stats[(size_t)k*128 + c];
            s2 += stats[(size_t)k*128 + 64 + c];
        }
        r1[tid] = s1;
        r2[tid] = s2;
    }
    __syncthreads();
    if (tid < 64) {
        float t1 = r1[tid] + r1[64+tid] + r1[128+tid] + r1[192+tid];
        float t2 = r2[tid] + r2[64+tid] + r2[128+tid] + r2[192+tid];
        float mean = t1 * (1.0f/16384.0f);
        float var  = t2 * (1.0f/16384.0f) - mean*mean;
        float sc = gamma[tid] * rsqrtf(var + EPSV);
        params[tid]      = sc;
        params[64 + tid] = beta[tid] - mean*sc;
    }
    __syncthreads();

    const float4* x4 = (const float4*)x;
    float4* o4 = (float4*)out;
    #pragma unroll
    for (int j = 0; j < 4; ++j) {
        int i4 = blockIdx.x*1024 + tid + 256*j;   // 262144 float4s total
        int cb = (i4 & 15) * 4;
        float4 v  = o4[i4];
        float4 xv = x4[i4];
        float4 sc = *(const float4*)&params[cb];
        float4 sh = *(const float4*)&params[64 + cb];
        float4 rr;
        rr.x = xv.x + sc.x*v.x + sh.x;
        rr.y = xv.y + sc.y*v.y + sh.y;
        rr.z = xv.z + sc.z*v.z + sh.z;
        rr.w = xv.w + sc.w*v.w + sh.w;
        o4[i4] = rr;
    }
}

// ---------------------------------------------------------------------------
extern "C" void kernel_launch(void* const* d_in, const int* in_sizes, int n_in,
                              void* d_out, int out_size, void* d_ws, size_t ws_size,
                              hipStream_t stream)
{
    const float* x     = (const float*)d_in[0];
    const float* gW    = (const float*)d_in[1];
    const float* gb    = (const float*)d_in[2];
    const float* pW    = (const float*)d_in[3];
    const float* pb    = (const float*)d_in[4];
    const float* tW    = (const float*)d_in[5];
    const float* tb    = (const float*)d_in[6];
    const float* wW    = (const float*)d_in[7];
    const float* wb    = (const float*)d_in[8];
    const float* gamma = (const float*)d_in[9];
    const float* beta  = (const float*)d_in[10];
    float* out = (float*)d_out;

    char* w = (char*)d_ws;
    __hip_bfloat16* thetab = (__hip_bfloat16*)(w);                 // 1 MB
    __hip_bfloat16* phib   = (__hip_bfloat16*)(w + (1u<<20));      // 1 MB
    __hip_bfloat16* gshuf  = (__hip_bfloat16*)(w + (2u<<20));      // 1 MB
    float* stats  = (float*)(w + (3u<<20));                        // 256 KB

    proj_kernel<<<512, 256, 0, stream>>>(x, gW, gb, pW, pb, tW, tb, thetab, phib, gshuf);
    attn_kernel<<<512, 512, 0, stream>>>(thetab, phib, gshuf, wW, wb, out, stats);
    apply_kernel<<<256, 256, 0, stream>>>(stats, gamma, beta, x, out);
}

// Round 6
// 63.376 us; speedup vs baseline: 2.6856x; 1.2678x over previous
//
#include <hip/hip_runtime.h>
#include <hip/hip_bf16.h>
#include <cstddef>
#include <cstdint>

#define EPSV 1e-3f
#define LOG2E 1.4426950408889634f

using f32x4 = __attribute__((ext_vector_type(4))) float;
using bh8   = __attribute__((ext_vector_type(8))) short;   // 8 bf16

#if defined(__has_builtin)
#  if __has_builtin(__builtin_amdgcn_exp2f)
#    define EXP2F(v) __builtin_amdgcn_exp2f(v)
#  else
#    define EXP2F(v) exp2f(v)
#  endif
#else
#  define EXP2F(v) exp2f(v)
#endif

// packed f32x2 -> bf16x2 (RNE), one VALU op
static __device__ __forceinline__ uint32_t cvtpk(float lo, float hi) {
    uint32_t r;
    asm("v_cvt_pk_bf16_f32 %0, %1, %2" : "=v"(r) : "v"(lo), "v"(hi));
    return r;
}

// ---------------------------------------------------------------------------
// Kernel 1: projections. 512 blocks x 32 pixels. theta/phi: [pix][32] bf16;
// theta pre-scaled by log2(e) so attention uses native exp2.
// g stored PRE-SHUFFLED transposed gshuf[b][d][4096]; within each 32-key
// chunk, position 8h+i holds key kappa(h,i) = i<4 ? 4h+i : 16+4h+(i-4),
// matching the PV A-fragment key order (verified rounds 1-5 passing).
// ---------------------------------------------------------------------------
__global__ __launch_bounds__(256) void proj_kernel(
    const float* __restrict__ x,
    const float* __restrict__ gW, const float* __restrict__ gbias,
    const float* __restrict__ pW, const float* __restrict__ pbias,
    const float* __restrict__ tW, const float* __restrict__ tbias,
    __hip_bfloat16* __restrict__ thetab,
    __hip_bfloat16* __restrict__ phib,
    __hip_bfloat16* __restrict__ gshuf)
{
    __shared__ float lx[32*65];
    __shared__ float lw[3*2048];       // theta, phi, g weights [64c][32o]
    __shared__ float lbias[96];
    const int tid = threadIdx.x;
    const int pix0 = blockIdx.x * 32;

    #pragma unroll
    for (int j = 0; j < 8; ++j) {      // 2048 floats of x
        int idx = tid + 256*j;
        lx[(idx >> 6)*65 + (idx & 63)] = x[(size_t)pix0*64 + idx];
    }
    #pragma unroll
    for (int j = 0; j < 8; ++j) {
        int idx = tid + 256*j;
        lw[idx]        = tW[idx];
        lw[2048 + idx] = pW[idx];
        lw[4096 + idx] = gW[idx];
    }
    if (tid < 32) { lbias[tid] = tbias[tid]; lbias[32+tid] = pbias[tid]; lbias[64+tid] = gbias[tid]; }
    __syncthreads();

    const int p  = tid & 31;
    const int og = tid >> 5;           // 0..7 -> 12 outputs each (96 total)
    const int obase = og*12;
    float acc[12];
    #pragma unroll
    for (int j = 0; j < 12; ++j) acc[j] = 0.f;
    for (int c = 0; c < 64; ++c) {
        float xc = lx[p*65 + c];
        #pragma unroll
        for (int j = 0; j < 12; ++j) {
            int o = obase + j;
            acc[j] += xc * lw[(o >> 5)*2048 + c*32 + (o & 31)];
        }
    }
    const int pix = pix0 + p;
    const int b = pix >> 12;
    const int n = pix & 4095;
    const int loc = n & 31;
    const int t  = (loc >> 4) & 1;
    const int hh = (loc >> 2) & 3;
    const int jj = loc & 3;
    const int pos = (n & ~31) + 8*hh + jj + 4*t;
    #pragma unroll
    for (int j = 0; j < 12; ++j) {
        int o = obase + j;
        float v = acc[j] + lbias[o];
        if (o < 32)       thetab[(size_t)pix*32 + o] = __float2bfloat16(v * LOG2E);
        else if (o < 64)  phib[(size_t)pix*32 + (o-32)] = __float2bfloat16(v);
        else              gshuf[((size_t)b*32 + (o-64))*4096 + pos] = __float2bfloat16(v);
    }
}

// ---------------------------------------------------------------------------
// Kernel 2: fused flash-attention + output conv + BN partial stats.
// 256 blocks (4 batch x 64 qtiles of SIXTY-FOUR queries), 8 waves =
// 2 query-halves x 4 key-quarters; wave (qh,kq) does 32 queries over keys
// [kq*1024, kq*1024+1024). Each phi/G byte serves 64 queries -> L2 traffic
// halved vs 32q blocks. Swapped-operand QK^T + kmap-baked gshuf: exp'd
// scores feed PV A-fragment directly (v_cvt_pk_bf16_f32 packing).
// Cross-wave combine in LDS -> normalized y -> y @ w_W + w_b -> out
// (pre-BN), plus per-block channel sum/sumsq -> stats.
// ---------------------------------------------------------------------------
__global__ __launch_bounds__(512, 4) void attn_kernel(
    const __hip_bfloat16* __restrict__ thetab,
    const __hip_bfloat16* __restrict__ phib,
    const __hip_bfloat16* __restrict__ gshuf,
    const float* __restrict__ wW, const float* __restrict__ wb,
    float* __restrict__ out, float* __restrict__ stats)
{
    __shared__ float yl[8][32][33];    // 33.8 KB
    __shared__ float lred[8][32];
    __shared__ float lwW[2048];
    __shared__ float lwb[64];
    const int tid  = threadIdx.x;
    const int wave = tid >> 6;
    const int lane = tid & 63;
    const int h = lane >> 4;
    const int r = lane & 15;
    const int blk = blockIdx.x;
    const int b = blk >> 6;            // 64 q-blocks per batch
    const int q0 = (blk & 63) * 64;
    const int qh = wave >> 2;          // query half 0/1
    const int kq = wave & 3;           // key quarter
    const int qbase = q0 + qh*32;
    const size_t base = (size_t)b * 4096;

    #pragma unroll
    for (int j = 0; j < 4; ++j) lwW[tid + 512*j] = wW[tid + 512*j];
    if (tid < 64) lwb[tid] = wb[tid];

    const bh8 qaA = *(const bh8*)(thetab + (base + qbase + r)*32 + h*8);
    const bh8 qaB = *(const bh8*)(thetab + (base + qbase + 16 + r)*32 + h*8);
    const __hip_bfloat16* phiB = phib  + base*32;
    const __hip_bfloat16* gB   = gshuf + base*32;

    f32x4 y0A = {0,0,0,0}, y1A = {0,0,0,0};
    f32x4 y0B = {0,0,0,0}, y1B = {0,0,0,0};
    float lsA = 0.f, lsB = 0.f;

    const int kbeg = kq * 1024;
    const int kend = kbeg + 1024;
    bh8 ka = *(const bh8*)(phiB + (size_t)(kbeg + r)*32 + h*8);
    bh8 kb = *(const bh8*)(phiB + (size_t)(kbeg + 16 + r)*32 + h*8);
    bh8 g0 = *(const bh8*)(gB + (size_t)r*4096 + kbeg + 8*h);
    bh8 g1 = *(const bh8*)(gB + (size_t)(16 + r)*4096 + kbeg + 8*h);

    for (int kk = kbeg; kk < kend; kk += 32) {
        const int nk = (kk + 32 < kend) ? (kk + 32) : kbeg;   // depth-1 prefetch
        bh8 ka2 = *(const bh8*)(phiB + (size_t)(nk + r)*32 + h*8);
        bh8 kb2 = *(const bh8*)(phiB + (size_t)(nk + 16 + r)*32 + h*8);
        bh8 g02 = *(const bh8*)(gB + (size_t)r*4096 + nk + 8*h);
        bh8 g12 = *(const bh8*)(gB + (size_t)(16 + r)*4096 + nk + 8*h);

        f32x4 z = {0,0,0,0};
        f32x4 s0A = __builtin_amdgcn_mfma_f32_16x16x32_bf16(ka, qaA, z, 0, 0, 0);
        f32x4 s1A = __builtin_amdgcn_mfma_f32_16x16x32_bf16(kb, qaA, z, 0, 0, 0);
        f32x4 s0B = __builtin_amdgcn_mfma_f32_16x16x32_bf16(ka, qaB, z, 0, 0, 0);
        f32x4 s1B = __builtin_amdgcn_mfma_f32_16x16x32_bf16(kb, qaB, z, 0, 0, 0);

        float pA0 = EXP2F(s0A[0]), pA1 = EXP2F(s0A[1]), pA2 = EXP2F(s0A[2]), pA3 = EXP2F(s0A[3]);
        float pA4 = EXP2F(s1A[0]), pA5 = EXP2F(s1A[1]), pA6 = EXP2F(s1A[2]), pA7 = EXP2F(s1A[3]);
        float pB0 = EXP2F(s0B[0]), pB1 = EXP2F(s0B[1]), pB2 = EXP2F(s0B[2]), pB3 = EXP2F(s0B[3]);
        float pB4 = EXP2F(s1B[0]), pB5 = EXP2F(s1B[1]), pB6 = EXP2F(s1B[2]), pB7 = EXP2F(s1B[3]);
        lsA += ((pA0+pA1)+(pA2+pA3)) + ((pA4+pA5)+(pA6+pA7));
        lsB += ((pB0+pB1)+(pB2+pB3)) + ((pB4+pB5)+(pB6+pB7));

        union { uint32_t u[4]; bh8 v; } pkA, pkB;
        pkA.u[0] = cvtpk(pA0, pA1); pkA.u[1] = cvtpk(pA2, pA3);
        pkA.u[2] = cvtpk(pA4, pA5); pkA.u[3] = cvtpk(pA6, pA7);
        pkB.u[0] = cvtpk(pB0, pB1); pkB.u[1] = cvtpk(pB2, pB3);
        pkB.u[2] = cvtpk(pB4, pB5); pkB.u[3] = cvtpk(pB6, pB7);

        y0A = __builtin_amdgcn_mfma_f32_16x16x32_bf16(pkA.v, g0, y0A, 0, 0, 0);
        y1A = __builtin_amdgcn_mfma_f32_16x16x32_bf16(pkA.v, g1, y1A, 0, 0, 0);
        y0B = __builtin_amdgcn_mfma_f32_16x16x32_bf16(pkB.v, g0, y0B, 0, 0, 0);
        y1B = __builtin_amdgcn_mfma_f32_16x16x32_bf16(pkB.v, g1, y1B, 0, 0, 0);

        ka = ka2; kb = kb2; g0 = g02; g1 = g12;
    }

    lsA += __shfl_xor(lsA, 16); lsA += __shfl_xor(lsA, 32);
    lsB += __shfl_xor(lsB, 16); lsB += __shfl_xor(lsB, 32);

    #pragma unroll
    for (int gi = 0; gi < 4; ++gi) {
        yl[wave][4*h+gi][r]       = y0A[gi];
        yl[wave][4*h+gi][16+r]    = y1A[gi];
        yl[wave][16+4*h+gi][r]    = y0B[gi];
        yl[wave][16+4*h+gi][16+r] = y1B[gi];
    }
    if (lane < 16) { lred[wave][r] = lsA; lred[wave][16+r] = lsB; }
    __syncthreads();

    // Phase B: combine 4 key-quarter waves per query half + normalize.
    // Thread owns (q = tid>>3 in 0..63, d4 = (tid&7)*4): reads its 4 source
    // cells, overwrites only its own yl[(q>>5)*4] cells -> hazard-free.
    {
        const int q   = tid >> 3;
        const int d4  = (tid & 7) * 4;
        const int qh2 = q >> 5;
        const int ql  = q & 31;
        float a0=0.f, a1=0.f, a2=0.f, a3=0.f, lq=0.f;
        #pragma unroll
        for (int w = 0; w < 4; ++w) {
            a0 += yl[qh2*4+w][ql][d4+0];
            a1 += yl[qh2*4+w][ql][d4+1];
            a2 += yl[qh2*4+w][ql][d4+2];
            a3 += yl[qh2*4+w][ql][d4+3];
            lq += lred[qh2*4+w][ql];
        }
        float inv = 1.0f / lq;
        yl[qh2*4][ql][d4+0] = a0*inv;
        yl[qh2*4][ql][d4+1] = a1*inv;
        yl[qh2*4][ql][d4+2] = a2*inv;
        yl[qh2*4][ql][d4+3] = a3*inv;
    }
    __syncthreads();

    // Phase C: w_y = y @ w_W + w_b -> out (pre-BN); channel sum/sumsq.
    // Wave cg_ handles channels cg_*8..+8 for all 64 pixels (lane = pixel).
    {
        const int p   = lane;              // pixel within block (0..63)
        const int cg_ = wave;              // channel group (0..7)
        float acc[8];
        #pragma unroll
        for (int j = 0; j < 8; ++j) acc[j] = lwb[cg_*8 + j];
        for (int d = 0; d < 32; ++d) {
            float yv = yl[(p >> 5)*4][p & 31][d];
            #pragma unroll
            for (int j = 0; j < 8; ++j) acc[j] += yv * lwW[d*64 + cg_*8 + j];
        }
        *(float4*)(out + (size_t)(base + q0 + p)*64 + cg_*8)     = *(float4*)&acc[0];
        *(float4*)(out + (size_t)(base + q0 + p)*64 + cg_*8 + 4) = *(float4*)&acc[4];

        float s1[8], s2[8];
        #pragma unroll
        for (int j = 0; j < 8; ++j) { s1[j] = acc[j]; s2[j] = acc[j]*acc[j]; }
        #pragma unroll
        for (int m = 1; m <= 32; m <<= 1) {
            #pragma unroll
            for (int j = 0; j < 8; ++j) {
                s1[j] += __shfl_xor(s1[j], m);
                s2[j] += __shfl_xor(s2[j], m);
            }
        }
        if (lane == 0) {
            #pragma unroll
            for (int j = 0; j < 8; ++j) {
                stats[(size_t)blk*128 + cg_*8 + j]      = s1[j];
                stats[(size_t)blk*128 + 64 + cg_*8 + j] = s2[j];
            }
        }
    }
}

// ---------------------------------------------------------------------------
// Kernel 3: fused BN-finalize + apply. 256 blocks x 256 threads.
// Every block redundantly reduces the 256x128 stat partials, computes
// scale/shift in LDS, then out = x + sc*w_y + sh for its slice.
// ---------------------------------------------------------------------------
__global__ __launch_bounds__(256) void apply_kernel(
    const float* __restrict__ stats,
    const float* __restrict__ gamma,
    const float* __restrict__ beta,
    const float* __restrict__ x,
    float* __restrict__ out)
{
    __shared__ float r1[256];
    __shared__ float r2[256];
    __shared__ __align__(16) float params[128];
    const int tid = threadIdx.x;
    {
        const int c = tid & 63, part = tid >> 6;
        float s1 = 0.f, s2 = 0.f;
        for (int k = part*64; k < part*64 + 64; ++k) {
            s1 += stats[(size_t)k*128 + c];
            s2 += stats[(size_t)k*128 + 64 + c];
        }
        r1[tid] = s1;
        r2[tid] = s2;
    }
    __syncthreads();
    if (tid < 64) {
        float t1 = r1[tid] + r1[64+tid] + r1[128+tid] + r1[192+tid];
        float t2 = r2[tid] + r2[64+tid] + r2[128+tid] + r2[192+tid];
        float mean = t1 * (1.0f/16384.0f);
        float var  = t2 * (1.0f/16384.0f) - mean*mean;
        float sc = gamma[tid] * rsqrtf(var + EPSV);
        params[tid]      = sc;
        params[64 + tid] = beta[tid] - mean*sc;
    }
    __syncthreads();

    const float4* x4 = (const float4*)x;
    float4* o4 = (float4*)out;
    #pragma unroll
    for (int j = 0; j < 4; ++j) {
        int i4 = blockIdx.x*1024 + tid + 256*j;   // 262144 float4s total
        int cb = (i4 & 15) * 4;
        float4 v  = o4[i4];
        float4 xv = x4[i4];
        float4 sc = *(const float4*)&params[cb];
        float4 sh = *(const float4*)&params[64 + cb];
        float4 rr;
        rr.x = xv.x + sc.x*v.x + sh.x;
        rr.y = xv.y + sc.y*v.y + sh.y;
        rr.z = xv.z + sc.z*v.z + sh.z;
        rr.w = xv.w + sc.w*v.w + sh.w;
        o4[i4] = rr;
    }
}

// ---------------------------------------------------------------------------
extern "C" void kernel_launch(void* const* d_in, const int* in_sizes, int n_in,
                              void* d_out, int out_size, void* d_ws, size_t ws_size,
                              hipStream_t stream)
{
    const float* x     = (const float*)d_in[0];
    const float* gW    = (const float*)d_in[1];
    const float* gb    = (const float*)d_in[2];
    const float* pW    = (const float*)d_in[3];
    const float* pb    = (const float*)d_in[4];
    const float* tW    = (const float*)d_in[5];
    const float* tb    = (const float*)d_in[6];
    const float* wW    = (const float*)d_in[7];
    const float* wb    = (const float*)d_in[8];
    const float* gamma = (const float*)d_in[9];
    const float* beta  = (const float*)d_in[10];
    float* out = (float*)d_out;

    char* w = (char*)d_ws;
    __hip_bfloat16* thetab = (__hip_bfloat16*)(w);                 // 1 MB
    __hip_bfloat16* phib   = (__hip_bfloat16*)(w + (1u<<20));      // 1 MB
    __hip_bfloat16* gshuf  = (__hip_bfloat16*)(w + (2u<<20));      // 1 MB
    float* stats  = (float*)(w + (3u<<20));                        // 128 KB

    proj_kernel<<<512, 256, 0, stream>>>(x, gW, gb, pW, pb, tW, tb, thetab, phib, gshuf);
    attn_kernel<<<256, 512, 0, stream>>>(thetab, phib, gshuf, wW, wb, out, stats);
    apply_kernel<<<256, 256, 0, stream>>>(stats, gamma, beta, x, out);
}

// Round 7
// 51.635 us; speedup vs baseline: 3.2963x; 1.2274x over previous
//
#include <hip/hip_runtime.h>
#include <hip/hip_bf16.h>
#include <cstddef>
#include <cstdint>

#define EPSV 1e-3f
#define LOG2E 1.4426950408889634f

using f32x4 = __attribute__((ext_vector_type(4))) float;
using bh8   = __attribute__((ext_vector_type(8))) short;   // 8 bf16

#if defined(__has_builtin)
#  if __has_builtin(__builtin_amdgcn_exp2f)
#    define EXP2F(v) __builtin_amdgcn_exp2f(v)
#  else
#    define EXP2F(v) exp2f(v)
#  endif
#else
#  define EXP2F(v) exp2f(v)
#endif

// packed f32x2 -> bf16x2 (RNE), one VALU op
static __device__ __forceinline__ uint32_t cvtpk(float lo, float hi) {
    uint32_t r;
    asm("v_cvt_pk_bf16_f32 %0, %1, %2" : "=v"(r) : "v"(lo), "v"(hi));
    return r;
}

// ---------------------------------------------------------------------------
// Kernel 1: projections. 512 blocks x 32 pixels. theta/phi: [pix][32] bf16;
// theta pre-scaled by log2(e) so attention uses native exp2.
// g stored PRE-SHUFFLED transposed gshuf[b][d][4096]; within each 32-key
// chunk, position 8h+i holds key kappa(h,i) = i<4 ? 4h+i : 16+4h+(i-4),
// matching the PV A-fragment key order (verified rounds 1-6 passing).
// ---------------------------------------------------------------------------
__global__ __launch_bounds__(256) void proj_kernel(
    const float* __restrict__ x,
    const float* __restrict__ gW, const float* __restrict__ gbias,
    const float* __restrict__ pW, const float* __restrict__ pbias,
    const float* __restrict__ tW, const float* __restrict__ tbias,
    __hip_bfloat16* __restrict__ thetab,
    __hip_bfloat16* __restrict__ phib,
    __hip_bfloat16* __restrict__ gshuf)
{
    __shared__ float lx[32*65];
    __shared__ float lw[3*2048];       // theta, phi, g weights [64c][32o]
    __shared__ float lbias[96];
    const int tid = threadIdx.x;
    const int pix0 = blockIdx.x * 32;

    #pragma unroll
    for (int j = 0; j < 8; ++j) {      // 2048 floats of x
        int idx = tid + 256*j;
        lx[(idx >> 6)*65 + (idx & 63)] = x[(size_t)pix0*64 + idx];
    }
    #pragma unroll
    for (int j = 0; j < 8; ++j) {
        int idx = tid + 256*j;
        lw[idx]        = tW[idx];
        lw[2048 + idx] = pW[idx];
        lw[4096 + idx] = gW[idx];
    }
    if (tid < 32) { lbias[tid] = tbias[tid]; lbias[32+tid] = pbias[tid]; lbias[64+tid] = gbias[tid]; }
    __syncthreads();

    const int p  = tid & 31;
    const int og = tid >> 5;           // 0..7 -> 12 outputs each (96 total)
    const int obase = og*12;
    float acc[12];
    #pragma unroll
    for (int j = 0; j < 12; ++j) acc[j] = 0.f;
    for (int c = 0; c < 64; ++c) {
        float xc = lx[p*65 + c];
        #pragma unroll
        for (int j = 0; j < 12; ++j) {
            int o = obase + j;
            acc[j] += xc * lw[(o >> 5)*2048 + c*32 + (o & 31)];
        }
    }
    const int pix = pix0 + p;
    const int b = pix >> 12;
    const int n = pix & 4095;
    const int loc = n & 31;
    const int t  = (loc >> 4) & 1;
    const int hh = (loc >> 2) & 3;
    const int jj = loc & 3;
    const int pos = (n & ~31) + 8*hh + jj + 4*t;
    #pragma unroll
    for (int j = 0; j < 12; ++j) {
        int o = obase + j;
        float v = acc[j] + lbias[o];
        if (o < 32)       thetab[(size_t)pix*32 + o] = __float2bfloat16(v * LOG2E);
        else if (o < 64)  phib[(size_t)pix*32 + (o-32)] = __float2bfloat16(v);
        else              gshuf[((size_t)b*32 + (o-64))*4096 + pos] = __float2bfloat16(v);
    }
}

// ---------------------------------------------------------------------------
// Kernel 2: fused flash-attention + output conv + BN partial stats.
// 256 blocks (4 batch x 64 qtiles of 64 queries) x 1024 threads = 16 waves
// = 2 query-halves x 8 key-octants; wave (qh,kq) does 32 queries over keys
// [kq*512, kq*512+512). 1 block/CU -> 16 waves/CU = 4 waves/SIMD.
// Each phi/G byte serves 64 queries (128 MB total L2 traffic).
// Swapped-operand QK^T + kmap-baked gshuf: exp'd scores feed PV A-fragment
// directly (v_cvt_pk_bf16_f32 packing). Cross-wave combine in LDS ->
// normalized y -> y @ w_W + w_b -> out (pre-BN) + channel sum/sumsq stats.
// ---------------------------------------------------------------------------
__global__ __launch_bounds__(1024, 4) void attn_kernel(
    const __hip_bfloat16* __restrict__ thetab,
    const __hip_bfloat16* __restrict__ phib,
    const __hip_bfloat16* __restrict__ gshuf,
    const float* __restrict__ wW, const float* __restrict__ wb,
    float* __restrict__ out, float* __restrict__ stats)
{
    __shared__ float yl[16][32][33];   // 67.6 KB
    __shared__ float lred[16][32];
    __shared__ float lwW[2048];
    __shared__ float lwb[64];
    const int tid  = threadIdx.x;
    const int wave = tid >> 6;
    const int lane = tid & 63;
    const int h = lane >> 4;
    const int r = lane & 15;
    const int blk = blockIdx.x;
    const int b = blk >> 6;            // 64 q-blocks per batch
    const int q0 = (blk & 63) * 64;
    const int qh = wave >> 3;          // query half 0/1
    const int kq = wave & 7;           // key octant
    const int qbase = q0 + qh*32;
    const size_t base = (size_t)b * 4096;

    #pragma unroll
    for (int j = 0; j < 2; ++j) lwW[tid + 1024*j] = wW[tid + 1024*j];
    if (tid < 64) lwb[tid] = wb[tid];

    const bh8 qaA = *(const bh8*)(thetab + (base + qbase + r)*32 + h*8);
    const bh8 qaB = *(const bh8*)(thetab + (base + qbase + 16 + r)*32 + h*8);
    const __hip_bfloat16* phiB = phib  + base*32;
    const __hip_bfloat16* gB   = gshuf + base*32;

    f32x4 y0A = {0,0,0,0}, y1A = {0,0,0,0};
    f32x4 y0B = {0,0,0,0}, y1B = {0,0,0,0};
    float lsA = 0.f, lsB = 0.f;

    const int kbeg = kq * 512;
    const int kend = kbeg + 512;
    bh8 ka = *(const bh8*)(phiB + (size_t)(kbeg + r)*32 + h*8);
    bh8 kb = *(const bh8*)(phiB + (size_t)(kbeg + 16 + r)*32 + h*8);
    bh8 g0 = *(const bh8*)(gB + (size_t)r*4096 + kbeg + 8*h);
    bh8 g1 = *(const bh8*)(gB + (size_t)(16 + r)*4096 + kbeg + 8*h);

    for (int kk = kbeg; kk < kend; kk += 32) {
        const int nk = (kk + 32 < kend) ? (kk + 32) : kbeg;   // depth-1 prefetch
        bh8 ka2 = *(const bh8*)(phiB + (size_t)(nk + r)*32 + h*8);
        bh8 kb2 = *(const bh8*)(phiB + (size_t)(nk + 16 + r)*32 + h*8);
        bh8 g02 = *(const bh8*)(gB + (size_t)r*4096 + nk + 8*h);
        bh8 g12 = *(const bh8*)(gB + (size_t)(16 + r)*4096 + nk + 8*h);

        f32x4 z = {0,0,0,0};
        f32x4 s0A = __builtin_amdgcn_mfma_f32_16x16x32_bf16(ka, qaA, z, 0, 0, 0);
        f32x4 s1A = __builtin_amdgcn_mfma_f32_16x16x32_bf16(kb, qaA, z, 0, 0, 0);
        f32x4 s0B = __builtin_amdgcn_mfma_f32_16x16x32_bf16(ka, qaB, z, 0, 0, 0);
        f32x4 s1B = __builtin_amdgcn_mfma_f32_16x16x32_bf16(kb, qaB, z, 0, 0, 0);

        float pA0 = EXP2F(s0A[0]), pA1 = EXP2F(s0A[1]), pA2 = EXP2F(s0A[2]), pA3 = EXP2F(s0A[3]);
        float pA4 = EXP2F(s1A[0]), pA5 = EXP2F(s1A[1]), pA6 = EXP2F(s1A[2]), pA7 = EXP2F(s1A[3]);
        float pB0 = EXP2F(s0B[0]), pB1 = EXP2F(s0B[1]), pB2 = EXP2F(s0B[2]), pB3 = EXP2F(s0B[3]);
        float pB4 = EXP2F(s1B[0]), pB5 = EXP2F(s1B[1]), pB6 = EXP2F(s1B[2]), pB7 = EXP2F(s1B[3]);
        lsA += ((pA0+pA1)+(pA2+pA3)) + ((pA4+pA5)+(pA6+pA7));
        lsB += ((pB0+pB1)+(pB2+pB3)) + ((pB4+pB5)+(pB6+pB7));

        union { uint32_t u[4]; bh8 v; } pkA, pkB;
        pkA.u[0] = cvtpk(pA0, pA1); pkA.u[1] = cvtpk(pA2, pA3);
        pkA.u[2] = cvtpk(pA4, pA5); pkA.u[3] = cvtpk(pA6, pA7);
        pkB.u[0] = cvtpk(pB0, pB1); pkB.u[1] = cvtpk(pB2, pB3);
        pkB.u[2] = cvtpk(pB4, pB5); pkB.u[3] = cvtpk(pB6, pB7);

        y0A = __builtin_amdgcn_mfma_f32_16x16x32_bf16(pkA.v, g0, y0A, 0, 0, 0);
        y1A = __builtin_amdgcn_mfma_f32_16x16x32_bf16(pkA.v, g1, y1A, 0, 0, 0);
        y0B = __builtin_amdgcn_mfma_f32_16x16x32_bf16(pkB.v, g0, y0B, 0, 0, 0);
        y1B = __builtin_amdgcn_mfma_f32_16x16x32_bf16(pkB.v, g1, y1B, 0, 0, 0);

        ka = ka2; kb = kb2; g0 = g02; g1 = g12;
    }

    lsA += __shfl_xor(lsA, 16); lsA += __shfl_xor(lsA, 32);
    lsB += __shfl_xor(lsB, 16); lsB += __shfl_xor(lsB, 32);

    #pragma unroll
    for (int gi = 0; gi < 4; ++gi) {
        yl[wave][4*h+gi][r]       = y0A[gi];
        yl[wave][4*h+gi][16+r]    = y1A[gi];
        yl[wave][16+4*h+gi][r]    = y0B[gi];
        yl[wave][16+4*h+gi][16+r] = y1B[gi];
    }
    if (lane < 16) { lred[wave][r] = lsA; lred[wave][16+r] = lsB; }
    __syncthreads();

    // Phase B: combine 8 key-octant waves per query half + normalize.
    // Thread owns (q = tid>>4 in 0..63, d2 = (tid&15)*2): reads its 8 source
    // cells, overwrites only its own yl[(q>>5)*8] cells -> hazard-free.
    {
        const int q   = tid >> 4;
        const int d2  = (tid & 15) * 2;
        const int qh2 = q >> 5;
        const int ql  = q & 31;
        float a0=0.f, a1=0.f, lq=0.f;
        #pragma unroll
        for (int w = 0; w < 8; ++w) {
            a0 += yl[qh2*8+w][ql][d2];
            a1 += yl[qh2*8+w][ql][d2+1];
            lq += lred[qh2*8+w][ql];
        }
        float inv = 1.0f / lq;
        yl[qh2*8][ql][d2]   = a0*inv;
        yl[qh2*8][ql][d2+1] = a1*inv;
    }
    __syncthreads();

    // Phase C: w_y = y @ w_W + w_b -> out (pre-BN); channel sum/sumsq.
    // Wave cg_ handles channels cg_*4..+4 for all 64 pixels (lane = pixel).
    {
        const int p   = lane;              // pixel within block (0..63)
        const int cg_ = wave;              // channel group (0..15)
        float acc[4];
        #pragma unroll
        for (int j = 0; j < 4; ++j) acc[j] = lwb[cg_*4 + j];
        for (int d = 0; d < 32; ++d) {
            float yv = yl[(p >> 5)*8][p & 31][d];
            #pragma unroll
            for (int j = 0; j < 4; ++j) acc[j] += yv * lwW[d*64 + cg_*4 + j];
        }
        *(float4*)(out + (size_t)(base + q0 + p)*64 + cg_*4) = *(float4*)&acc[0];

        float s1[4], s2[4];
        #pragma unroll
        for (int j = 0; j < 4; ++j) { s1[j] = acc[j]; s2[j] = acc[j]*acc[j]; }
        #pragma unroll
        for (int m = 1; m <= 32; m <<= 1) {
            #pragma unroll
            for (int j = 0; j < 4; ++j) {
                s1[j] += __shfl_xor(s1[j], m);
                s2[j] += __shfl_xor(s2[j], m);
            }
        }
        if (lane == 0) {
            #pragma unroll
            for (int j = 0; j < 4; ++j) {
                stats[(size_t)blk*128 + cg_*4 + j]      = s1[j];
                stats[(size_t)blk*128 + 64 + cg_*4 + j] = s2[j];
            }
        }
    }
}

// ---------------------------------------------------------------------------
// Kernel 3: fused BN-finalize + apply. 256 blocks x 256 threads.
// Every block redundantly reduces the 256x128 stat partials (unrolled for
// load ILP), computes scale/shift in LDS, then out = x + sc*w_y + sh.
// ---------------------------------------------------------------------------
__global__ __launch_bounds__(256) void apply_kernel(
    const float* __restrict__ stats,
    const float* __restrict__ gamma,
    const float* __restrict__ beta,
    const float* __restrict__ x,
    float* __restrict__ out)
{
    __shared__ float r1[256];
    __shared__ float r2[256];
    __shared__ __align__(16) float params[128];
    const int tid = threadIdx.x;
    {
        const int c = tid & 63, part = tid >> 6;
        float s1 = 0.f, s2 = 0.f;
        #pragma unroll 8
        for (int k = part*64; k < part*64 + 64; ++k) {
            s1 += stats[(size_t)k*128 + c];
            s2 += stats[(size_t)k*128 + 64 + c];
        }
        r1[tid] = s1;
        r2[tid] = s2;
    }
    __syncthreads();
    if (tid < 64) {
        float t1 = r1[tid] + r1[64+tid] + r1[128+tid] + r1[192+tid];
        float t2 = r2[tid] + r2[64+tid] + r2[128+tid] + r2[192+tid];
        float mean = t1 * (1.0f/16384.0f);
        float var  = t2 * (1.0f/16384.0f) - mean*mean;
        float sc = gamma[tid] * rsqrtf(var + EPSV);
        params[tid]      = sc;
        params[64 + tid] = beta[tid] - mean*sc;
    }
    __syncthreads();

    const float4* x4 = (const float4*)x;
    float4* o4 = (float4*)out;
    #pragma unroll
    for (int j = 0; j < 4; ++j) {
        int i4 = blockIdx.x*1024 + tid + 256*j;   // 262144 float4s total
        int cb = (i4 & 15) * 4;
        float4 v  = o4[i4];
        float4 xv = x4[i4];
        float4 sc = *(const float4*)&params[cb];
        float4 sh = *(const float4*)&params[64 + cb];
        float4 rr;
        rr.x = xv.x + sc.x*v.x + sh.x;
        rr.y = xv.y + sc.y*v.y + sh.y;
        rr.z = xv.z + sc.z*v.z + sh.z;
        rr.w = xv.w + sc.w*v.w + sh.w;
        o4[i4] = rr;
    }
}

// ---------------------------------------------------------------------------
extern "C" void kernel_launch(void* const* d_in, const int* in_sizes, int n_in,
                              void* d_out, int out_size, void* d_ws, size_t ws_size,
                              hipStream_t stream)
{
    const float* x     = (const float*)d_in[0];
    const float* gW    = (const float*)d_in[1];
    const float* gb    = (const float*)d_in[2];
    const float* pW    = (const float*)d_in[3];
    const float* pb    = (const float*)d_in[4];
    const float* tW    = (const float*)d_in[5];
    const float* tb    = (const float*)d_in[6];
    const float* wW    = (const float*)d_in[7];
    const float* wb    = (const float*)d_in[8];
    const float* gamma = (const float*)d_in[9];
    const float* beta  = (const float*)d_in[10];
    float* out = (float*)d_out;

    char* w = (char*)d_ws;
    __hip_bfloat16* thetab = (__hip_bfloat16*)(w);                 // 1 MB
    __hip_bfloat16* phib   = (__hip_bfloat16*)(w + (1u<<20));      // 1 MB
    __hip_bfloat16* gshuf  = (__hip_bfloat16*)(w + (2u<<20));      // 1 MB
    float* stats  = (float*)(w + (3u<<20));                        // 128 KB

    proj_kernel<<<512, 256, 0, stream>>>(x, gW, gb, pW, pb, tW, tb, thetab, phib, gshuf);
    attn_kernel<<<256, 1024, 0, stream>>>(thetab, phib, gshuf, wW, wb, out, stats);
    apply_kernel<<<256, 256, 0, stream>>>(stats, gamma, beta, x, out);
}